// Round 18
// baseline (467.235 us; speedup 1.0000x reference)
//
#include <hip/hip_runtime.h>

typedef unsigned short u16;
typedef unsigned int u32;
typedef unsigned long long u64;

#define E_TOT 202752   // B*N0*DEG = 32*1584*4
#define NMAX  50688    // B*N0
#define HEADS 4
#define B_    32
#define MAXDEG 32      // Poisson(4) in-degree: P(>=32) ~ 1e-18/node — safe bucket
#define REMAP_Y 25     // CDIV(E_TOT, 32*256)
#define TRE_TBLK 3168  // transform blocks for L0 = NMAX/16
#define TRE_EBLK 792   // edge-init blocks = CDIV(E_TOT,256)

#define CDIV(a,b) (((a)+(b)-1)/(b))

// order-preserving float->uint map (monotonic); code 0 is below any real float's code
__device__ __forceinline__ u32 ford(float f) {
  u32 u = __float_as_uint(f);
  return (u & 0x80000000u) ? ~u : (u | 0x80000000u);
}
__device__ __forceinline__ float ford_inv(u32 u) {
  u32 b = (u & 0x80000000u) ? (u ^ 0x80000000u) : ~u;
  return __uint_as_float(b);
}

// DPP row-rotate (16-lane row) move; CTRL = 0x120 | n for row_ror:n
template <int CTRL>
__device__ __forceinline__ float dpp_mov(float x) {
  return __int_as_float(__builtin_amdgcn_mov_dpp(__float_as_int(x), CTRL, 0xF, 0xF, false));
}
// sum over each 16-lane row via VALU-pipe rotations (no DS pipe on the hot path)
__device__ __forceinline__ float row16_sum(float v) {
  v += dpp_mov<0x121>(v);   // row_ror:1
  v += dpp_mov<0x122>(v);   // row_ror:2
  v += dpp_mov<0x124>(v);   // row_ror:4
  v += dpp_mov<0x128>(v);   // row_ror:8
  return v;
}

__device__ __forceinline__ u64 shfl_xor_u64(u64 v, int mask) {
  int lo = __shfl_xor((int)(u32)(v & 0xFFFFFFFFu), mask, 64);
  int hi = __shfl_xor((int)(u32)(v >> 32), mask, 64);
  return ((u64)(u32)hi << 32) | (u32)lo;
}

// ---------- FUSED: node transform L0 (FIN=32) + edge-array/CSR init in ONE launch.
// Measured R15/R16: part of the 477.8->460.4 wins. Blocks [0,TRE_TBLK): transform;
// blocks [TRE_TBLK,+TRE_EBLK): edge init. Fully independent roles, width preserved.
__global__ void k_tre(const float* __restrict__ hin,
                      const float* __restrict__ Wl, const float* __restrict__ bl,
                      const float* __restrict__ Wr, const float* __restrict__ br,
                      float* __restrict__ xl, float* __restrict__ xr,
                      const int* __restrict__ ei, int* __restrict__ src,
                      int* __restrict__ dst, int* __restrict__ em,
                      int* __restrict__ cnt, int* __restrict__ csr) {
  __shared__ float xs[32][20];
  int j = threadIdx.x;
  if (blockIdx.x >= TRE_TBLK) {          // ---- edge-init role ----
    int e = (blockIdx.x - TRE_TBLK) * 256 + j;
    if (e >= E_TOT) return;
    int s = ei[e], d = ei[E_TOT + e];
    src[e] = s;
    dst[e] = d;
    em[e] = 1;
    int pos = atomicAdd(&cnt[d], 1);
    if (pos < MAXDEG) csr[d * MAXDEG + pos] = e;
    return;
  }
  // ---- transform role (verified k_transform_t<32> body) ----
  int n0 = blockIdx.x * 16;
  for (int t = j; t < 16 * 32; t += 256) {
    int nd = t >> 5, f = t & 31;
    xs[f][nd] = hin[(size_t)(n0 + nd) * 32 + f];
  }
  __syncthreads();
  float al[16], ar[16];
  float blv = bl[j], brv = br[j];
#pragma unroll
  for (int t = 0; t < 16; ++t) { al[t] = blv; ar[t] = brv; }
  for (int i = 0; i < 32; ++i) {
    float wl = Wl[i * 256 + j], wr = Wr[i * 256 + j];
    float4 x0 = *(const float4*)&xs[i][0];
    float4 x1 = *(const float4*)&xs[i][4];
    float4 x2 = *(const float4*)&xs[i][8];
    float4 x3 = *(const float4*)&xs[i][12];
    al[0]  += x0.x * wl; ar[0]  += x0.x * wr;
    al[1]  += x0.y * wl; ar[1]  += x0.y * wr;
    al[2]  += x0.z * wl; ar[2]  += x0.z * wr;
    al[3]  += x0.w * wl; ar[3]  += x0.w * wr;
    al[4]  += x1.x * wl; ar[4]  += x1.x * wr;
    al[5]  += x1.y * wl; ar[5]  += x1.y * wr;
    al[6]  += x1.z * wl; ar[6]  += x1.z * wr;
    al[7]  += x1.w * wl; ar[7]  += x1.w * wr;
    al[8]  += x2.x * wl; ar[8]  += x2.x * wr;
    al[9]  += x2.y * wl; ar[9]  += x2.y * wr;
    al[10] += x2.z * wl; ar[10] += x2.z * wr;
    al[11] += x2.w * wl; ar[11] += x2.w * wr;
    al[12] += x3.x * wl; ar[12] += x3.x * wr;
    al[13] += x3.y * wl; ar[13] += x3.y * wr;
    al[14] += x3.z * wl; ar[14] += x3.z * wr;
    al[15] += x3.w * wl; ar[15] += x3.w * wr;
  }
#pragma unroll
  for (int t = 0; t < 16; ++t) {
    xl[(size_t)(n0 + t) * 256 + j] = al[t];
    xr[(size_t)(n0 + t) * 256 + j] = ar[t];
  }
}

// ---------- node transform for layers 1,2 (FIN=64) — unchanged verified version ----
template <int FIN>
__global__ void k_transform_t(const float* __restrict__ hin,
                              const float* __restrict__ Wl, const float* __restrict__ bl,
                              const float* __restrict__ Wr, const float* __restrict__ br,
                              float* __restrict__ xl, float* __restrict__ xr) {
  __shared__ float xs[FIN][20];
  int n0 = blockIdx.x * 16, j = threadIdx.x;   // 256 threads
  for (int t = j; t < 16 * FIN; t += 256) {
    int nd = t >> (FIN == 32 ? 5 : 6), f = t & (FIN - 1);
    xs[f][nd] = hin[(size_t)(n0 + nd) * FIN + f];
  }
  __syncthreads();
  float al[16], ar[16];
  float blv = bl[j], brv = br[j];
#pragma unroll
  for (int t = 0; t < 16; ++t) { al[t] = blv; ar[t] = brv; }
  for (int i = 0; i < FIN; ++i) {
    float wl = Wl[i * 256 + j], wr = Wr[i * 256 + j];
    float4 x0 = *(const float4*)&xs[i][0];     // broadcast b128 reads
    float4 x1 = *(const float4*)&xs[i][4];
    float4 x2 = *(const float4*)&xs[i][8];
    float4 x3 = *(const float4*)&xs[i][12];
    al[0]  += x0.x * wl; ar[0]  += x0.x * wr;
    al[1]  += x0.y * wl; ar[1]  += x0.y * wr;
    al[2]  += x0.z * wl; ar[2]  += x0.z * wr;
    al[3]  += x0.w * wl; ar[3]  += x0.w * wr;
    al[4]  += x1.x * wl; ar[4]  += x1.x * wr;
    al[5]  += x1.y * wl; ar[5]  += x1.y * wr;
    al[6]  += x1.z * wl; ar[6]  += x1.z * wr;
    al[7]  += x1.w * wl; ar[7]  += x1.w * wr;
    al[8]  += x2.x * wl; ar[8]  += x2.x * wr;
    al[9]  += x2.y * wl; ar[9]  += x2.y * wr;
    al[10] += x2.z * wl; ar[10] += x2.z * wr;
    al[11] += x2.w * wl; ar[11] += x2.w * wr;
    al[12] += x3.x * wl; ar[12] += x3.x * wr;
    al[13] += x3.y * wl; ar[13] += x3.y * wr;
    al[14] += x3.z * wl; ar[14] += x3.z * wr;
    al[15] += x3.w * wl; ar[15] += x3.w * wr;
  }
#pragma unroll
  for (int t = 0; t < 16; ++t) {
    xl[(size_t)(n0 + t) * 256 + j] = al[t];
    xr[(size_t)(n0 + t) * 256 + j] = ar[t];
  }
}

// ---------- fused GATv2 — R6 math + T5 setprio (R17: 456.4us, VALUBusy 48->51%).
// R18 refinement: prio-1 window EXTENDED through the epilogue — finishing the
// shuffle/tanh/store burst sooner lets this wave issue its next node's gathers
// sooner (same mechanism that paid in R17). Prio drops only around the load-issue
// phase at loop top. Canaries: VGPR 56, WRITE ~13MB, FETCH ~78MB.
__global__ void k_gat_fused(const int* __restrict__ srcv, const int* __restrict__ cnt,
                            const int* __restrict__ csr, const float* __restrict__ ea,
                            const float* __restrict__ We, const float* __restrict__ att,
                            const float* __restrict__ xl, const float* __restrict__ xr,
                            const float* __restrict__ bias, const float* __restrict__ pwv,
                            float* __restrict__ out, float* __restrict__ sc,
                            int n_per) {
  int b = blockIdx.x;
  int xcd = b & 7;
  int jj = b >> 3;                                 // 0..255 within XCD
  int g = xcd + 8 * (jj >> 6);                     // graph 0..31, g%8 == xcd
  int wv = ((jj & 63) << 2) + (threadIdx.x >> 6);  // wave-in-graph 0..255
  int lane = threadIdx.x & 63;
  int cg = lane & 15;
  int cb = (lane >> 4) * 64 + cg * 4;              // this lane's 4 channels
  int npw = CDIV(n_per, 256);
  int l0 = wv * npw, l1 = min(n_per, l0 + npw);
  if (l0 >= n_per) return;
  int n0 = g * n_per + l0, n1 = g * n_per + l1;
  // per-layer constants, hoisted once per wave
  float4 at4 = *(const float4*)(att + cb);
  float4 w0 = *(const float4*)(We + 0 * 256 + cb);
  float4 w1 = *(const float4*)(We + 1 * 256 + cb);
  float4 w2 = *(const float4*)(We + 2 * 256 + cb);
  float4 w3 = *(const float4*)(We + 3 * 256 + cb);
  float4 w4_ = *(const float4*)(We + 4 * 256 + cb);
  float4 w5 = *(const float4*)(We + 5 * 256 + cb);
  float4 w6 = *(const float4*)(We + 6 * 256 + cb);
  float4 w7 = *(const float4*)(We + 7 * 256 + cb);
  float4 bi4 = *(const float4*)(bias + cg * 4);
  float4 pw4 = *(const float4*)(pwv + cg * 4);
  float wn = pw4.x * pw4.x + pw4.y * pw4.y + pw4.z * pw4.z + pw4.w * pw4.w;
  wn += __shfl_xor(wn, 1, 64); wn += __shfl_xor(wn, 2, 64);
  wn += __shfl_xor(wn, 4, 64); wn += __shfl_xor(wn, 8, 64);
  float isq = 1.f / sqrtf(wn);

  // pipeline prologue: first node's metadata + xr row in flight
  int degc = cnt[n0];
  int e_c = (lane < MAXDEG) ? csr[n0 * MAXDEG + lane] : 0;
  int s_c = srcv[e_c];                            // garbage beyond deg: masked later
  float4 xdc = *(const float4*)(xr + (size_t)n0 * 256 + cb);

  for (int n = n0; n < n1; ++n) {
    // issue NEXT node's loads first (prio 0): they drain while we compute this node
    int degn = 0, e_n = 0, s_n = 0;
    float4 xdn = xdc;
    if (n + 1 < n1) {
      degn = cnt[n + 1];
      e_n = (lane < MAXDEG) ? csr[(n + 1) * MAXDEG + lane] : 0;
      s_n = srcv[e_n];
      xdn = *(const float4*)(xr + (size_t)(n + 1) * 256 + cb);
    }
    int deg = min(degc, MAXDEG);
    int e_l = e_c, s_l = s_c;
    float4 xd4 = xdc;
    float m = -INFINITY, l = 0.f;
    float ox = 0.f, oy = 0.f, oz = 0.f, ow = 0.f;
    for (int i0 = 0; i0 < deg; i0 += 4) {
      int c0 = deg - i0; if (c0 > 4) c0 = 4;       // wave-uniform
      float4 xs[4], a0[4], a1[4];
#pragma unroll
      for (int j = 0; j < 4; ++j) {
        int idx = (j < c0) ? (i0 + j) : i0;        // clamp to a safe slot (uniform)
        int e = __builtin_amdgcn_readlane(e_l, idx);   // VALU->SGPR broadcast
        int s = __builtin_amdgcn_readlane(s_l, idx);
        xs[j] = *(const float4*)(xl + (size_t)s * 256 + cb);   // independent, in flight
        a0[j] = *(const float4*)(ea + (size_t)e * 8);
        a1[j] = *(const float4*)(ea + (size_t)e * 8 + 4);
      }
      __builtin_amdgcn_s_setprio(1);     // data-ready wave: prefer its VALU burst
      // --- logits for the whole chunk, fully independent across j ---
      float v[4];
#pragma unroll
      for (int j = 0; j < 4; ++j) {
        if (j < c0) {
          float e0 = a0[j].x * w0.x + a0[j].y * w1.x + a0[j].z * w2.x + a0[j].w * w3.x
                   + a1[j].x * w4_.x + a1[j].y * w5.x + a1[j].z * w6.x + a1[j].w * w7.x;
          float e1 = a0[j].x * w0.y + a0[j].y * w1.y + a0[j].z * w2.y + a0[j].w * w3.y
                   + a1[j].x * w4_.y + a1[j].y * w5.y + a1[j].z * w6.y + a1[j].w * w7.y;
          float e2 = a0[j].x * w0.z + a0[j].y * w1.z + a0[j].z * w2.z + a0[j].w * w3.z
                   + a1[j].x * w4_.z + a1[j].y * w5.z + a1[j].z * w6.z + a1[j].w * w7.z;
          float e3 = a0[j].x * w0.w + a0[j].y * w1.w + a0[j].z * w2.w + a0[j].w * w3.w
                   + a1[j].x * w4_.w + a1[j].y * w5.w + a1[j].z * w6.w + a1[j].w * w7.w;
          float m0 = xs[j].x + xd4.x + e0; m0 = (m0 >= 0.f) ? m0 : 0.2f * m0;  // leaky
          float m1 = xs[j].y + xd4.y + e1; m1 = (m1 >= 0.f) ? m1 : 0.2f * m1;
          float m2 = xs[j].z + xd4.z + e2; m2 = (m2 >= 0.f) ? m2 : 0.2f * m2;
          float m3 = xs[j].w + xd4.w + e3; m3 = (m3 >= 0.f) ? m3 : 0.2f * m3;
          float d = at4.x * m0 + at4.y * m1 + at4.z * m2 + at4.w * m3;
          v[j] = row16_sum(d);           // 4 independent DPP chains interleave on VALU
        } else {
          v[j] = -INFINITY;              // pad slot: p=exp(-inf-nm)=0, no contribution
        }
      }
      // --- ONE max + rescale for the whole chunk ---
      float vm = fmaxf(fmaxf(v[0], v[1]), fmaxf(v[2], v[3]));
      float nm = fmaxf(m, vm);
      float scale = __expf(m - nm);      // first chunk: m=-inf -> scale=0
      float p0 = __expf(v[0] - nm), p1 = __expf(v[1] - nm);
      float p2 = __expf(v[2] - nm), p3 = __expf(v[3] - nm);
      ox = ox * scale + ((p0 * xs[0].x + p1 * xs[1].x) + (p2 * xs[2].x + p3 * xs[3].x));
      oy = oy * scale + ((p0 * xs[0].y + p1 * xs[1].y) + (p2 * xs[2].y + p3 * xs[3].y));
      oz = oz * scale + ((p0 * xs[0].z + p1 * xs[1].z) + (p2 * xs[2].z + p3 * xs[3].z));
      ow = ow * scale + ((p0 * xs[0].w + p1 * xs[1].w) + (p2 * xs[2].w + p3 * xs[3].w));
      l = l * scale + ((p0 + p1) + (p2 + p3));
      m = nm;
      // prio stays 1 through remaining chunks + epilogue (R18: extended window)
    }
    // epilogue at prio 1: finishing sooner -> next node's gathers issue sooner
    float inv = 0.25f / fmaxf(l, 1e-16f);
    float r0 = ox * inv, r1 = oy * inv, r2 = oz * inv, r3 = ow * inv;
    r0 += __shfl_xor(r0, 16, 64); r0 += __shfl_xor(r0, 32, 64);
    r1 += __shfl_xor(r1, 16, 64); r1 += __shfl_xor(r1, 32, 64);
    r2 += __shfl_xor(r2, 16, 64); r2 += __shfl_xor(r2, 32, 64);
    r3 += __shfl_xor(r3, 16, 64); r3 += __shfl_xor(r3, 32, 64);
    float rr0 = fmaxf(r0 + bi4.x, 0.f), rr1 = fmaxf(r1 + bi4.y, 0.f);
    float rr2 = fmaxf(r2 + bi4.z, 0.f), rr3 = fmaxf(r3 + bi4.w, 0.f);
    if (lane < 16) *(float4*)(out + (size_t)n * 64 + cg * 4) = float4{rr0, rr1, rr2, rr3};
    // topk score: s = tanh(h.w / ||w||)
    float dot = rr0 * pw4.x + rr1 * pw4.y + rr2 * pw4.z + rr3 * pw4.w;
    dot += __shfl_xor(dot, 1, 64);
    dot += __shfl_xor(dot, 2, 64);
    dot += __shfl_xor(dot, 4, 64);
    dot += __shfl_xor(dot, 8, 64);
    if (lane == 0) sc[n] = tanhf(dot * isq);
    __builtin_amdgcn_s_setprio(0);       // drop before next load-issue phase
    // rotate pipeline registers
    degc = degn; e_c = e_n; s_c = s_n; xdc = xdn;
  }
}

// stable descending top-k per graph — u64 keys (ford(score)<<32 | ~idx).
// Hybrid bitonic over 2048 elements, 2 elements/thread in registers (measured R6).
// Also zeroes cnt[0, B*k) for the next layer (replaces a hipMemsetAsync).
__global__ __launch_bounds__(1024) void k_topk(const float* __restrict__ s, int n_per,
                                               int k,
                                               int* __restrict__ perm, int* __restrict__ new_id,
                                               int* __restrict__ cnt) {
  __shared__ u64 kv[2048];
  int b = blockIdx.x, t = threadIdx.x;
  int base = b * n_per;
  for (int i = t; i < n_per; i += 1024) new_id[base + i] = -1;
  for (int i = t; i < k; i += 1024) cnt[b * k + i] = 0;   // next layer's CSR counters

  u64 e0, e1;
  {
    u32 sk0 = (t < n_per) ? ford(s[base + t]) : 0u;             // pad key 0: below all
    int i1 = t + 1024;
    u32 sk1 = (i1 < n_per) ? ford(s[base + i1]) : 0u;
    e0 = ((u64)sk0 << 32) | (u32)(0xFFFFFFFFu - (u32)t);        // tie -> lower idx first
    e1 = ((u64)sk1 << 32) | (u32)(0xFFFFFFFFu - (u32)i1);
  }

  for (int kk = 2; kk <= 2048; kk <<= 1) {
    int j = kk >> 1;
    if (j == 1024) {                     // partner of element t is element t+1024: local
      u64 mx = e0 > e1 ? e0 : e1;
      u64 mn = e0 > e1 ? e1 : e0;
      e0 = mx; e1 = mn;
      j >>= 1;
    }
    for (; j >= 64; j >>= 1) {           // cross-wave: LDS exchange
      __syncthreads();                   // prior pass's reads complete before overwrite
      kv[t] = e0; kv[t + 1024] = e1;
      __syncthreads();
      u64 p0 = kv[t ^ j], p1 = kv[(t + 1024) ^ j];
      int i1 = t + 1024;
      bool km0 = (((t  & kk) == 0) == ((t  & j) == 0));
      bool km1 = (((i1 & kk) == 0) == ((i1 & j) == 0));
      e0 = km0 ? (e0 > p0 ? e0 : p0) : (e0 < p0 ? e0 : p0);
      e1 = km1 ? (e1 > p1 ? e1 : p1) : (e1 < p1 ? e1 : p1);
    }
    for (; j >= 1; j >>= 1) {            // intra-wave: shuffle exchange, no barriers
      u64 p0 = shfl_xor_u64(e0, j);
      u64 p1 = shfl_xor_u64(e1, j);
      int i1 = t + 1024;
      bool km0 = (((t  & kk) == 0) == ((t  & j) == 0));
      bool km1 = (((i1 & kk) == 0) == ((i1 & j) == 0));
      e0 = km0 ? (e0 > p0 ? e0 : p0) : (e0 < p0 ? e0 : p0);
      e1 = km1 ? (e1 > p1 ? e1 : p1) : (e1 < p1 ? e1 : p1);
    }
  }

  // element i holds rank i (descending): e0 = rank t, e1 = rank t+1024
  if (t < k) {
    int old0 = (int)(0xFFFFFFFFu - (u32)(e0 & 0xFFFFFFFFu));
    perm[b * k + t] = base + old0;
    new_id[base + old0] = b * k + t;
  }
  int r1 = t + 1024;
  if (r1 < k) {
    int old1 = (int)(0xFFFFFFFFu - (u32)(e1 & 0xFFFFFFFFu));
    perm[b * k + r1] = base + old1;
    new_id[base + old1] = b * k + r1;
  }
}

// fused post-pool: WIDE gather+readout AND edge remap in ONE launch (measured good;
// R10 narrow fusion and R12 spin fusion both regressed — width matters).
// grid: dim3(32, gather_rows [+ REMAP_Y when do_remap]).
__global__ void k_post(const float* __restrict__ hin, const float* __restrict__ s,
                       const int* __restrict__ perm, float* __restrict__ hout,
                       int k, int gather_rows,
                       float* __restrict__ rsum, u32* __restrict__ rmaxI,
                       int* __restrict__ src, int* __restrict__ dst, int* __restrict__ em,
                       const int* __restrict__ new_id, int* __restrict__ cnt,
                       int* __restrict__ csr, int do_remap) {
  __shared__ float ps[256], pm[256];
  int b = blockIdx.x, yy = blockIdx.y, t = threadIdx.x;
  if (yy < gather_rows) {
    int i = yy * 4 + (t >> 6);            // local kept-node index
    int c = t & 63;
    bool valid = i < k;
    float v = 0.f;
    if (valid) {
      int g = perm[b * k + i];
      v = hin[(size_t)g * 64 + c] * s[g];
      hout[((size_t)b * k + i) * 64 + c] = v;
    }
    ps[t] = valid ? v : 0.f;
    pm[t] = valid ? v : -INFINITY;
    __syncthreads();
    if (t < 64) {
      float s4 = ps[t] + ps[t + 64] + ps[t + 128] + ps[t + 192];
      float m4 = fmaxf(fmaxf(pm[t], pm[t + 64]), fmaxf(pm[t + 128], pm[t + 192]));
      atomicAdd(&rsum[b * 64 + t], s4);
      atomicMax(&rmaxI[b * 64 + t], ford(m4));
    }
  } else if (do_remap) {
    int e = ((yy - gather_rows) * 32 + b) * 256 + t;
    if (e < E_TOT) {
      int ns = new_id[src[e]], nd = new_id[dst[e]];
      int mm = em[e] && ns >= 0 && nd >= 0;
      src[e] = mm ? ns : 0;
      dst[e] = mm ? nd : 0;
      em[e] = mm;
      if (mm) {
        int pos = atomicAdd(&cnt[nd], 1);
        if (pos < MAXDEG) csr[nd * MAXDEG + pos] = e;
      }
    }
  }
}

// MLP with readout finalization folded in: reads [rsum|rmaxI] x 3 layers directly
__global__ void k_mlp(const char* __restrict__ rblk,
                      const float* __restrict__ W1, const float* __restrict__ b1,
                      const float* __restrict__ W2, const float* __restrict__ b2,
                      const float* __restrict__ W3, const float* __restrict__ b3,
                      float* __restrict__ out) {
  __shared__ float v0[128], v1[64], v2[64], lgts[16];
  int b = blockIdx.x, t = threadIdx.x;   // 64 threads
  const float* rs0 = (const float*)rblk;
  const u32*   rm0 = (const u32*)(rblk + 32 * 64 * 4);
  const float* rs1 = (const float*)(rblk + 32 * 128 * 4);
  const u32*   rm1 = (const u32*)(rblk + 32 * 128 * 4 + 32 * 64 * 4);
  const float* rs2 = (const float*)(rblk + 2 * 32 * 128 * 4);
  const u32*   rm2 = (const u32*)(rblk + 2 * 32 * 128 * 4 + 32 * 64 * 4);
  v0[t] = rs0[b * 64 + t] / 1268.f + rs1[b * 64 + t] / 1015.f + rs2[b * 64 + t] / 812.f;
  v0[64 + t] = ford_inv(rm0[b * 64 + t]) + ford_inv(rm1[b * 64 + t]) + ford_inv(rm2[b * 64 + t]);
  __syncthreads();
  float a = b1[t];
  for (int i = 0; i < 128; ++i) a += v0[i] * W1[i * 64 + t];
  v1[t] = fmaxf(a, 0.f);
  __syncthreads();
  a = b2[t];
  for (int i = 0; i < 64; ++i) a += v1[i] * W2[i * 64 + t];
  v2[t] = fmaxf(a, 0.f);
  __syncthreads();
  if (t < 16) {
    a = b3[t];
    for (int i = 0; i < 64; ++i) a += v2[i] * W3[i * 16 + t];
    lgts[t] = a;
  }
  __syncthreads();
  if (t == 0) {
    float m = lgts[0];
    for (int j = 1; j < 16; ++j) m = fmaxf(m, lgts[j]);
    float ex[16], sum = 0.f;
    for (int j = 0; j < 16; ++j) { ex[j] = expf(lgts[j] - m); sum += ex[j]; }
    for (int j = 0; j < 16; ++j) out[b * 16 + j] = ex[j] / sum;
  }
}

extern "C" void kernel_launch(void* const* d_in, const int* in_sizes, int n_in,
                              void* d_out, int out_size, void* d_ws, size_t ws_size,
                              hipStream_t stream) {
  (void)in_sizes; (void)n_in; (void)out_size; (void)ws_size;
  const float* x  = (const float*)d_in[0];      // [NMAX, 32] f32
  const float* ea = (const float*)d_in[1];      // [E, 8]     f32
  const int*   ei = (const int*)d_in[2];        // [2, E]

  const float *gWl[3], *gbl[3], *gWr[3], *gbr[3], *gWe[3], *gatt[3], *gb[3], *pw[3];
  for (int l = 0; l < 3; ++l) {
    int p0 = 4 + 7 * l;
    gWl[l]  = (const float*)d_in[p0 + 0];
    gbl[l]  = (const float*)d_in[p0 + 1];
    gWr[l]  = (const float*)d_in[p0 + 2];
    gbr[l]  = (const float*)d_in[p0 + 3];
    gWe[l]  = (const float*)d_in[p0 + 4];
    gatt[l] = (const float*)d_in[p0 + 5];
    gb[l]   = (const float*)d_in[p0 + 6];
    pw[l]   = (const float*)d_in[25 + l];
  }
  const float* fc1W = (const float*)d_in[28];
  const float* fc1b = (const float*)d_in[29];
  const float* fc2W = (const float*)d_in[30];
  const float* fc2b = (const float*)d_in[31];
  const float* fc3W = (const float*)d_in[32];
  const float* fc3b = (const float*)d_in[33];

  // ---- workspace carve. cnt|rblk|csr CONTIGUOUS (all sizes %256==0): ONE memset ----
  char* w = (char*)d_ws;
  size_t off = 0;
  auto alloc = [&](size_t bytes) -> void* {
    void* p = w + off;
    off += (bytes + 255) & ~(size_t)255;
    return p;
  };
  float* hbuf = (float*)alloc((size_t)B_ * 1268 * 64 * 4); // pooled features (max K1)
  float* xl   = (float*)alloc((size_t)NMAX * 256 * 4);     // source transform [N,256]
  float* xr   = (float*)alloc((size_t)NMAX * 256 * 4);     // target transform [N,256]
  float* nacc = (float*)alloc((size_t)NMAX * 64 * 4);      // fused GAT output (pre-pool)
  int*   cnt  = (int*)alloc((size_t)NMAX * 4);             // CSR degree counters
  char*  rblk = (char*)alloc(3 * 32 * 128 * 4);            // per-layer [rsum][rmaxI] x3
  int*   csr  = (int*)alloc((size_t)NMAX * MAXDEG * 4);
  float* sbuf = (float*)alloc((size_t)NMAX * 4);
  int* src    = (int*)alloc((size_t)E_TOT * 4);
  int* dst    = (int*)alloc((size_t)E_TOT * 4);
  int* em     = (int*)alloc((size_t)E_TOT * 4);
  int* new_id = (int*)alloc((size_t)NMAX * 4);
  int* perm   = (int*)alloc((size_t)32 * 1268 * 4);

  // one-time zero of cnt + rblk + csr (csr zero => every slot is an in-bounds edge id
  // forever, enabling k_gat_fused's unconditional csr/srcv prefetch)
  size_t zbytes = (size_t)NMAX * 4 + 3 * 32 * 128 * 4 + (size_t)NMAX * MAXDEG * 4;
  hipMemsetAsync(cnt, 0, zbytes, stream);

  const int Ns[3]    = {50688, 40576, 32480};   // B*N0, B*K1, B*K2 (all %16==0)
  const int npers[3] = {1584, 1268, 1015};
  const int ks[3]    = {1268, 1015, 812};
  const int GAT_BLOCKS = 2048;                  // 8 XCD x 4 graphs x 64 blocks

  for (int l = 0; l < 3; ++l) {
    int N = Ns[l];
    const float* hin = (l == 0) ? x : hbuf;
    float* rsum = (float*)(rblk + l * 32 * 128 * 4);
    u32* rmaxI  = (u32*)(rblk + l * 32 * 128 * 4 + 32 * 64 * 4);
    if (l == 0)
      k_tre<<<TRE_TBLK + TRE_EBLK, 256, 0, stream>>>(hin, gWl[l], gbl[l], gWr[l], gbr[l],
                                                     xl, xr, ei, src, dst, em, cnt, csr);
    else
      k_transform_t<64><<<N / 16, 256, 0, stream>>>(hin, gWl[l], gbl[l], gWr[l], gbr[l], xl, xr);
    k_gat_fused<<<GAT_BLOCKS, 256, 0, stream>>>(src, cnt, csr, ea, gWe[l], gatt[l],
                                                xl, xr, gb[l], pw[l], nacc, sbuf, npers[l]);
    k_topk<<<32, 1024, 0, stream>>>(sbuf, npers[l], ks[l], perm, new_id, cnt);
    int grows = CDIV(ks[l], 4);
    dim3 pgrid(32, grows + (l < 2 ? REMAP_Y : 0));
    k_post<<<pgrid, 256, 0, stream>>>(nacc, sbuf, perm, hbuf, ks[l], grows, rsum, rmaxI,
                                      src, dst, em, new_id, cnt, csr, (l < 2) ? 1 : 0);
  }
  k_mlp<<<32, 64, 0, stream>>>(rblk, fc1W, fc1b, fc2W, fc2b, fc3W, fc3b, (float*)d_out);
}

// Round 19
// 452.202 us; speedup vs baseline: 1.0332x; 1.0332x over previous
//
#include <hip/hip_runtime.h>

typedef unsigned short u16;
typedef unsigned int u32;
typedef unsigned long long u64;

#define E_TOT 202752   // B*N0*DEG = 32*1584*4
#define NMAX  50688    // B*N0
#define HEADS 4
#define B_    32
#define MAXDEG 32      // Poisson(4) in-degree: P(>=32) ~ 1e-18/node — safe bucket
#define REMAP_Y 25     // CDIV(E_TOT, 32*256)
#define TRE_TBLK 3168  // transform blocks for L0 = NMAX/16
#define TRE_EBLK 792   // edge-init blocks = CDIV(E_TOT,256)

#define CDIV(a,b) (((a)+(b)-1)/(b))

// order-preserving float->uint map (monotonic); code 0 is below any real float's code
__device__ __forceinline__ u32 ford(float f) {
  u32 u = __float_as_uint(f);
  return (u & 0x80000000u) ? ~u : (u | 0x80000000u);
}
__device__ __forceinline__ float ford_inv(u32 u) {
  u32 b = (u & 0x80000000u) ? (u ^ 0x80000000u) : ~u;
  return __uint_as_float(b);
}

// DPP row-rotate (16-lane row) move; CTRL = 0x120 | n for row_ror:n
template <int CTRL>
__device__ __forceinline__ float dpp_mov(float x) {
  return __int_as_float(__builtin_amdgcn_mov_dpp(__float_as_int(x), CTRL, 0xF, 0xF, false));
}
// sum over each 16-lane row via VALU-pipe rotations (no DS pipe on the hot path)
__device__ __forceinline__ float row16_sum(float v) {
  v += dpp_mov<0x121>(v);   // row_ror:1
  v += dpp_mov<0x122>(v);   // row_ror:2
  v += dpp_mov<0x124>(v);   // row_ror:4
  v += dpp_mov<0x128>(v);   // row_ror:8
  return v;
}

__device__ __forceinline__ u64 shfl_xor_u64(u64 v, int mask) {
  int lo = __shfl_xor((int)(u32)(v & 0xFFFFFFFFu), mask, 64);
  int hi = __shfl_xor((int)(u32)(v >> 32), mask, 64);
  return ((u64)(u32)hi << 32) | (u32)lo;
}

// ---------- FUSED: node transform L0 (FIN=32) + edge-array/CSR init in ONE launch.
// Measured R15/R16: part of the 477.8->460.4 wins. Blocks [0,TRE_TBLK): transform;
// blocks [TRE_TBLK,+TRE_EBLK): edge init. Fully independent roles, width preserved.
__global__ void k_tre(const float* __restrict__ hin,
                      const float* __restrict__ Wl, const float* __restrict__ bl,
                      const float* __restrict__ Wr, const float* __restrict__ br,
                      float* __restrict__ xl, float* __restrict__ xr,
                      const int* __restrict__ ei, int* __restrict__ src,
                      int* __restrict__ dst, int* __restrict__ em,
                      int* __restrict__ cnt, int* __restrict__ csr) {
  __shared__ float xs[32][20];
  int j = threadIdx.x;
  if (blockIdx.x >= TRE_TBLK) {          // ---- edge-init role ----
    int e = (blockIdx.x - TRE_TBLK) * 256 + j;
    if (e >= E_TOT) return;
    int s = ei[e], d = ei[E_TOT + e];
    src[e] = s;
    dst[e] = d;
    em[e] = 1;
    int pos = atomicAdd(&cnt[d], 1);
    if (pos < MAXDEG) csr[d * MAXDEG + pos] = e;
    return;
  }
  // ---- transform role (verified k_transform_t<32> body) ----
  int n0 = blockIdx.x * 16;
  for (int t = j; t < 16 * 32; t += 256) {
    int nd = t >> 5, f = t & 31;
    xs[f][nd] = hin[(size_t)(n0 + nd) * 32 + f];
  }
  __syncthreads();
  float al[16], ar[16];
  float blv = bl[j], brv = br[j];
#pragma unroll
  for (int t = 0; t < 16; ++t) { al[t] = blv; ar[t] = brv; }
  for (int i = 0; i < 32; ++i) {
    float wl = Wl[i * 256 + j], wr = Wr[i * 256 + j];
    float4 x0 = *(const float4*)&xs[i][0];
    float4 x1 = *(const float4*)&xs[i][4];
    float4 x2 = *(const float4*)&xs[i][8];
    float4 x3 = *(const float4*)&xs[i][12];
    al[0]  += x0.x * wl; ar[0]  += x0.x * wr;
    al[1]  += x0.y * wl; ar[1]  += x0.y * wr;
    al[2]  += x0.z * wl; ar[2]  += x0.z * wr;
    al[3]  += x0.w * wl; ar[3]  += x0.w * wr;
    al[4]  += x1.x * wl; ar[4]  += x1.x * wr;
    al[5]  += x1.y * wl; ar[5]  += x1.y * wr;
    al[6]  += x1.z * wl; ar[6]  += x1.z * wr;
    al[7]  += x1.w * wl; ar[7]  += x1.w * wr;
    al[8]  += x2.x * wl; ar[8]  += x2.x * wr;
    al[9]  += x2.y * wl; ar[9]  += x2.y * wr;
    al[10] += x2.z * wl; ar[10] += x2.z * wr;
    al[11] += x2.w * wl; ar[11] += x2.w * wr;
    al[12] += x3.x * wl; ar[12] += x3.x * wr;
    al[13] += x3.y * wl; ar[13] += x3.y * wr;
    al[14] += x3.z * wl; ar[14] += x3.z * wr;
    al[15] += x3.w * wl; ar[15] += x3.w * wr;
  }
#pragma unroll
  for (int t = 0; t < 16; ++t) {
    xl[(size_t)(n0 + t) * 256 + j] = al[t];
    xr[(size_t)(n0 + t) * 256 + j] = ar[t];
  }
}

// ---------- node transform for layers 1,2 (FIN=64) — unchanged verified version ----
template <int FIN>
__global__ void k_transform_t(const float* __restrict__ hin,
                              const float* __restrict__ Wl, const float* __restrict__ bl,
                              const float* __restrict__ Wr, const float* __restrict__ br,
                              float* __restrict__ xl, float* __restrict__ xr) {
  __shared__ float xs[FIN][20];
  int n0 = blockIdx.x * 16, j = threadIdx.x;   // 256 threads
  for (int t = j; t < 16 * FIN; t += 256) {
    int nd = t >> (FIN == 32 ? 5 : 6), f = t & (FIN - 1);
    xs[f][nd] = hin[(size_t)(n0 + nd) * FIN + f];
  }
  __syncthreads();
  float al[16], ar[16];
  float blv = bl[j], brv = br[j];
#pragma unroll
  for (int t = 0; t < 16; ++t) { al[t] = blv; ar[t] = brv; }
  for (int i = 0; i < FIN; ++i) {
    float wl = Wl[i * 256 + j], wr = Wr[i * 256 + j];
    float4 x0 = *(const float4*)&xs[i][0];     // broadcast b128 reads
    float4 x1 = *(const float4*)&xs[i][4];
    float4 x2 = *(const float4*)&xs[i][8];
    float4 x3 = *(const float4*)&xs[i][12];
    al[0]  += x0.x * wl; ar[0]  += x0.x * wr;
    al[1]  += x0.y * wl; ar[1]  += x0.y * wr;
    al[2]  += x0.z * wl; ar[2]  += x0.z * wr;
    al[3]  += x0.w * wl; ar[3]  += x0.w * wr;
    al[4]  += x1.x * wl; ar[4]  += x1.x * wr;
    al[5]  += x1.y * wl; ar[5]  += x1.y * wr;
    al[6]  += x1.z * wl; ar[6]  += x1.z * wr;
    al[7]  += x1.w * wl; ar[7]  += x1.w * wr;
    al[8]  += x2.x * wl; ar[8]  += x2.x * wr;
    al[9]  += x2.y * wl; ar[9]  += x2.y * wr;
    al[10] += x2.z * wl; ar[10] += x2.z * wr;
    al[11] += x2.w * wl; ar[11] += x2.w * wr;
    al[12] += x3.x * wl; ar[12] += x3.x * wr;
    al[13] += x3.y * wl; ar[13] += x3.y * wr;
    al[14] += x3.z * wl; ar[14] += x3.z * wr;
    al[15] += x3.w * wl; ar[15] += x3.w * wr;
  }
#pragma unroll
  for (int t = 0; t < 16; ++t) {
    xl[(size_t)(n0 + t) * 256 + j] = al[t];
    xr[(size_t)(n0 + t) * 256 + j] = ar[t];
  }
}

// ---------- fused GATv2 — EXACT R17-verified version (456.4us total, GAT steady
// ~64us, VALUBusy 51%, 56 VGPR). T5 setprio: prio-1 ONLY around the per-chunk
// compute burst (R18's extended-through-epilogue window regressed; reverted).
__global__ void k_gat_fused(const int* __restrict__ srcv, const int* __restrict__ cnt,
                            const int* __restrict__ csr, const float* __restrict__ ea,
                            const float* __restrict__ We, const float* __restrict__ att,
                            const float* __restrict__ xl, const float* __restrict__ xr,
                            const float* __restrict__ bias, const float* __restrict__ pwv,
                            float* __restrict__ out, float* __restrict__ sc,
                            int n_per) {
  int b = blockIdx.x;
  int xcd = b & 7;
  int jj = b >> 3;                                 // 0..255 within XCD
  int g = xcd + 8 * (jj >> 6);                     // graph 0..31, g%8 == xcd
  int wv = ((jj & 63) << 2) + (threadIdx.x >> 6);  // wave-in-graph 0..255
  int lane = threadIdx.x & 63;
  int cg = lane & 15;
  int cb = (lane >> 4) * 64 + cg * 4;              // this lane's 4 channels
  int npw = CDIV(n_per, 256);
  int l0 = wv * npw, l1 = min(n_per, l0 + npw);
  if (l0 >= n_per) return;
  int n0 = g * n_per + l0, n1 = g * n_per + l1;
  // per-layer constants, hoisted once per wave
  float4 at4 = *(const float4*)(att + cb);
  float4 w0 = *(const float4*)(We + 0 * 256 + cb);
  float4 w1 = *(const float4*)(We + 1 * 256 + cb);
  float4 w2 = *(const float4*)(We + 2 * 256 + cb);
  float4 w3 = *(const float4*)(We + 3 * 256 + cb);
  float4 w4_ = *(const float4*)(We + 4 * 256 + cb);
  float4 w5 = *(const float4*)(We + 5 * 256 + cb);
  float4 w6 = *(const float4*)(We + 6 * 256 + cb);
  float4 w7 = *(const float4*)(We + 7 * 256 + cb);
  float4 bi4 = *(const float4*)(bias + cg * 4);
  float4 pw4 = *(const float4*)(pwv + cg * 4);
  float wn = pw4.x * pw4.x + pw4.y * pw4.y + pw4.z * pw4.z + pw4.w * pw4.w;
  wn += __shfl_xor(wn, 1, 64); wn += __shfl_xor(wn, 2, 64);
  wn += __shfl_xor(wn, 4, 64); wn += __shfl_xor(wn, 8, 64);
  float isq = 1.f / sqrtf(wn);

  // pipeline prologue: first node's metadata + xr row in flight
  int degc = cnt[n0];
  int e_c = (lane < MAXDEG) ? csr[n0 * MAXDEG + lane] : 0;
  int s_c = srcv[e_c];                            // garbage beyond deg: masked later
  float4 xdc = *(const float4*)(xr + (size_t)n0 * 256 + cb);

  for (int n = n0; n < n1; ++n) {
    // issue NEXT node's loads first: they drain while we compute this node
    int degn = 0, e_n = 0, s_n = 0;
    float4 xdn = xdc;
    if (n + 1 < n1) {
      degn = cnt[n + 1];
      e_n = (lane < MAXDEG) ? csr[(n + 1) * MAXDEG + lane] : 0;
      s_n = srcv[e_n];
      xdn = *(const float4*)(xr + (size_t)(n + 1) * 256 + cb);
    }
    int deg = min(degc, MAXDEG);
    int e_l = e_c, s_l = s_c;
    float4 xd4 = xdc;
    float m = -INFINITY, l = 0.f;
    float ox = 0.f, oy = 0.f, oz = 0.f, ow = 0.f;
    for (int i0 = 0; i0 < deg; i0 += 4) {
      int c0 = deg - i0; if (c0 > 4) c0 = 4;       // wave-uniform
      float4 xs[4], a0[4], a1[4];
#pragma unroll
      for (int j = 0; j < 4; ++j) {
        int idx = (j < c0) ? (i0 + j) : i0;        // clamp to a safe slot (uniform)
        int e = __builtin_amdgcn_readlane(e_l, idx);   // VALU->SGPR broadcast
        int s = __builtin_amdgcn_readlane(s_l, idx);
        xs[j] = *(const float4*)(xl + (size_t)s * 256 + cb);   // independent, in flight
        a0[j] = *(const float4*)(ea + (size_t)e * 8);
        a1[j] = *(const float4*)(ea + (size_t)e * 8 + 4);
      }
      __builtin_amdgcn_s_setprio(1);     // data-ready wave: prefer its VALU burst
      // --- logits for the whole chunk, fully independent across j ---
      float v[4];
#pragma unroll
      for (int j = 0; j < 4; ++j) {
        if (j < c0) {
          float e0 = a0[j].x * w0.x + a0[j].y * w1.x + a0[j].z * w2.x + a0[j].w * w3.x
                   + a1[j].x * w4_.x + a1[j].y * w5.x + a1[j].z * w6.x + a1[j].w * w7.x;
          float e1 = a0[j].x * w0.y + a0[j].y * w1.y + a0[j].z * w2.y + a0[j].w * w3.y
                   + a1[j].x * w4_.y + a1[j].y * w5.y + a1[j].z * w6.y + a1[j].w * w7.y;
          float e2 = a0[j].x * w0.z + a0[j].y * w1.z + a0[j].z * w2.z + a0[j].w * w3.z
                   + a1[j].x * w4_.z + a1[j].y * w5.z + a1[j].z * w6.z + a1[j].w * w7.z;
          float e3 = a0[j].x * w0.w + a0[j].y * w1.w + a0[j].z * w2.w + a0[j].w * w3.w
                   + a1[j].x * w4_.w + a1[j].y * w5.w + a1[j].z * w6.w + a1[j].w * w7.w;
          float m0 = xs[j].x + xd4.x + e0; m0 = (m0 >= 0.f) ? m0 : 0.2f * m0;  // leaky
          float m1 = xs[j].y + xd4.y + e1; m1 = (m1 >= 0.f) ? m1 : 0.2f * m1;
          float m2 = xs[j].z + xd4.z + e2; m2 = (m2 >= 0.f) ? m2 : 0.2f * m2;
          float m3 = xs[j].w + xd4.w + e3; m3 = (m3 >= 0.f) ? m3 : 0.2f * m3;
          float d = at4.x * m0 + at4.y * m1 + at4.z * m2 + at4.w * m3;
          v[j] = row16_sum(d);           // 4 independent DPP chains interleave on VALU
        } else {
          v[j] = -INFINITY;              // pad slot: p=exp(-inf-nm)=0, no contribution
        }
      }
      // --- ONE max + rescale for the whole chunk ---
      float vm = fmaxf(fmaxf(v[0], v[1]), fmaxf(v[2], v[3]));
      float nm = fmaxf(m, vm);
      float scale = __expf(m - nm);      // first chunk: m=-inf -> scale=0
      float p0 = __expf(v[0] - nm), p1 = __expf(v[1] - nm);
      float p2 = __expf(v[2] - nm), p3 = __expf(v[3] - nm);
      ox = ox * scale + ((p0 * xs[0].x + p1 * xs[1].x) + (p2 * xs[2].x + p3 * xs[3].x));
      oy = oy * scale + ((p0 * xs[0].y + p1 * xs[1].y) + (p2 * xs[2].y + p3 * xs[3].y));
      oz = oz * scale + ((p0 * xs[0].z + p1 * xs[1].z) + (p2 * xs[2].z + p3 * xs[3].z));
      ow = ow * scale + ((p0 * xs[0].w + p1 * xs[1].w) + (p2 * xs[2].w + p3 * xs[3].w));
      l = l * scale + ((p0 + p1) + (p2 + p3));
      m = nm;
      __builtin_amdgcn_s_setprio(0);     // back to normal for the next gather wait
    }
    // per-head y = O/den, then 0.25 * head-sum  (deg==0 -> l=0 -> y=0, matches ref)
    float inv = 0.25f / fmaxf(l, 1e-16f);
    float r0 = ox * inv, r1 = oy * inv, r2 = oz * inv, r3 = ow * inv;
    r0 += __shfl_xor(r0, 16, 64); r0 += __shfl_xor(r0, 32, 64);
    r1 += __shfl_xor(r1, 16, 64); r1 += __shfl_xor(r1, 32, 64);
    r2 += __shfl_xor(r2, 16, 64); r2 += __shfl_xor(r2, 32, 64);
    r3 += __shfl_xor(r3, 16, 64); r3 += __shfl_xor(r3, 32, 64);
    float rr0 = fmaxf(r0 + bi4.x, 0.f), rr1 = fmaxf(r1 + bi4.y, 0.f);
    float rr2 = fmaxf(r2 + bi4.z, 0.f), rr3 = fmaxf(r3 + bi4.w, 0.f);
    if (lane < 16) *(float4*)(out + (size_t)n * 64 + cg * 4) = float4{rr0, rr1, rr2, rr3};
    // topk score: s = tanh(h.w / ||w||)
    float dot = rr0 * pw4.x + rr1 * pw4.y + rr2 * pw4.z + rr3 * pw4.w;
    dot += __shfl_xor(dot, 1, 64);
    dot += __shfl_xor(dot, 2, 64);
    dot += __shfl_xor(dot, 4, 64);
    dot += __shfl_xor(dot, 8, 64);
    if (lane == 0) sc[n] = tanhf(dot * isq);
    // rotate pipeline registers
    degc = degn; e_c = e_n; s_c = s_n; xdc = xdn;
  }
}

// stable descending top-k per graph — u64 keys (ford(score)<<32 | ~idx).
// Hybrid bitonic over 2048 elements, 2 elements/thread in registers (measured R6).
// Also zeroes cnt[0, B*k) for the next layer (replaces a hipMemsetAsync).
__global__ __launch_bounds__(1024) void k_topk(const float* __restrict__ s, int n_per,
                                               int k,
                                               int* __restrict__ perm, int* __restrict__ new_id,
                                               int* __restrict__ cnt) {
  __shared__ u64 kv[2048];
  int b = blockIdx.x, t = threadIdx.x;
  int base = b * n_per;
  for (int i = t; i < n_per; i += 1024) new_id[base + i] = -1;
  for (int i = t; i < k; i += 1024) cnt[b * k + i] = 0;   // next layer's CSR counters

  u64 e0, e1;
  {
    u32 sk0 = (t < n_per) ? ford(s[base + t]) : 0u;             // pad key 0: below all
    int i1 = t + 1024;
    u32 sk1 = (i1 < n_per) ? ford(s[base + i1]) : 0u;
    e0 = ((u64)sk0 << 32) | (u32)(0xFFFFFFFFu - (u32)t);        // tie -> lower idx first
    e1 = ((u64)sk1 << 32) | (u32)(0xFFFFFFFFu - (u32)i1);
  }

  for (int kk = 2; kk <= 2048; kk <<= 1) {
    int j = kk >> 1;
    if (j == 1024) {                     // partner of element t is element t+1024: local
      u64 mx = e0 > e1 ? e0 : e1;
      u64 mn = e0 > e1 ? e1 : e0;
      e0 = mx; e1 = mn;
      j >>= 1;
    }
    for (; j >= 64; j >>= 1) {           // cross-wave: LDS exchange
      __syncthreads();                   // prior pass's reads complete before overwrite
      kv[t] = e0; kv[t + 1024] = e1;
      __syncthreads();
      u64 p0 = kv[t ^ j], p1 = kv[(t + 1024) ^ j];
      int i1 = t + 1024;
      bool km0 = (((t  & kk) == 0) == ((t  & j) == 0));
      bool km1 = (((i1 & kk) == 0) == ((i1 & j) == 0));
      e0 = km0 ? (e0 > p0 ? e0 : p0) : (e0 < p0 ? e0 : p0);
      e1 = km1 ? (e1 > p1 ? e1 : p1) : (e1 < p1 ? e1 : p1);
    }
    for (; j >= 1; j >>= 1) {            // intra-wave: shuffle exchange, no barriers
      u64 p0 = shfl_xor_u64(e0, j);
      u64 p1 = shfl_xor_u64(e1, j);
      int i1 = t + 1024;
      bool km0 = (((t  & kk) == 0) == ((t  & j) == 0));
      bool km1 = (((i1 & kk) == 0) == ((i1 & j) == 0));
      e0 = km0 ? (e0 > p0 ? e0 : p0) : (e0 < p0 ? e0 : p0);
      e1 = km1 ? (e1 > p1 ? e1 : p1) : (e1 < p1 ? e1 : p1);
    }
  }

  // element i holds rank i (descending): e0 = rank t, e1 = rank t+1024
  if (t < k) {
    int old0 = (int)(0xFFFFFFFFu - (u32)(e0 & 0xFFFFFFFFu));
    perm[b * k + t] = base + old0;
    new_id[base + old0] = b * k + t;
  }
  int r1 = t + 1024;
  if (r1 < k) {
    int old1 = (int)(0xFFFFFFFFu - (u32)(e1 & 0xFFFFFFFFu));
    perm[b * k + r1] = base + old1;
    new_id[base + old1] = b * k + r1;
  }
}

// fused post-pool: WIDE gather+readout AND edge remap in ONE launch (measured good;
// R10 narrow fusion and R12 spin fusion both regressed — width matters).
// grid: dim3(32, gather_rows [+ REMAP_Y when do_remap]).
__global__ void k_post(const float* __restrict__ hin, const float* __restrict__ s,
                       const int* __restrict__ perm, float* __restrict__ hout,
                       int k, int gather_rows,
                       float* __restrict__ rsum, u32* __restrict__ rmaxI,
                       int* __restrict__ src, int* __restrict__ dst, int* __restrict__ em,
                       const int* __restrict__ new_id, int* __restrict__ cnt,
                       int* __restrict__ csr, int do_remap) {
  __shared__ float ps[256], pm[256];
  int b = blockIdx.x, yy = blockIdx.y, t = threadIdx.x;
  if (yy < gather_rows) {
    int i = yy * 4 + (t >> 6);            // local kept-node index
    int c = t & 63;
    bool valid = i < k;
    float v = 0.f;
    if (valid) {
      int g = perm[b * k + i];
      v = hin[(size_t)g * 64 + c] * s[g];
      hout[((size_t)b * k + i) * 64 + c] = v;
    }
    ps[t] = valid ? v : 0.f;
    pm[t] = valid ? v : -INFINITY;
    __syncthreads();
    if (t < 64) {
      float s4 = ps[t] + ps[t + 64] + ps[t + 128] + ps[t + 192];
      float m4 = fmaxf(fmaxf(pm[t], pm[t + 64]), fmaxf(pm[t + 128], pm[t + 192]));
      atomicAdd(&rsum[b * 64 + t], s4);
      atomicMax(&rmaxI[b * 64 + t], ford(m4));
    }
  } else if (do_remap) {
    int e = ((yy - gather_rows) * 32 + b) * 256 + t;
    if (e < E_TOT) {
      int ns = new_id[src[e]], nd = new_id[dst[e]];
      int mm = em[e] && ns >= 0 && nd >= 0;
      src[e] = mm ? ns : 0;
      dst[e] = mm ? nd : 0;
      em[e] = mm;
      if (mm) {
        int pos = atomicAdd(&cnt[nd], 1);
        if (pos < MAXDEG) csr[nd * MAXDEG + pos] = e;
      }
    }
  }
}

// MLP with readout finalization folded in: reads [rsum|rmaxI] x 3 layers directly
__global__ void k_mlp(const char* __restrict__ rblk,
                      const float* __restrict__ W1, const float* __restrict__ b1,
                      const float* __restrict__ W2, const float* __restrict__ b2,
                      const float* __restrict__ W3, const float* __restrict__ b3,
                      float* __restrict__ out) {
  __shared__ float v0[128], v1[64], v2[64], lgts[16];
  int b = blockIdx.x, t = threadIdx.x;   // 64 threads
  const float* rs0 = (const float*)rblk;
  const u32*   rm0 = (const u32*)(rblk + 32 * 64 * 4);
  const float* rs1 = (const float*)(rblk + 32 * 128 * 4);
  const u32*   rm1 = (const u32*)(rblk + 32 * 128 * 4 + 32 * 64 * 4);
  const float* rs2 = (const float*)(rblk + 2 * 32 * 128 * 4);
  const u32*   rm2 = (const u32*)(rblk + 2 * 32 * 128 * 4 + 32 * 64 * 4);
  v0[t] = rs0[b * 64 + t] / 1268.f + rs1[b * 64 + t] / 1015.f + rs2[b * 64 + t] / 812.f;
  v0[64 + t] = ford_inv(rm0[b * 64 + t]) + ford_inv(rm1[b * 64 + t]) + ford_inv(rm2[b * 64 + t]);
  __syncthreads();
  float a = b1[t];
  for (int i = 0; i < 128; ++i) a += v0[i] * W1[i * 64 + t];
  v1[t] = fmaxf(a, 0.f);
  __syncthreads();
  a = b2[t];
  for (int i = 0; i < 64; ++i) a += v1[i] * W2[i * 64 + t];
  v2[t] = fmaxf(a, 0.f);
  __syncthreads();
  if (t < 16) {
    a = b3[t];
    for (int i = 0; i < 64; ++i) a += v2[i] * W3[i * 16 + t];
    lgts[t] = a;
  }
  __syncthreads();
  if (t == 0) {
    float m = lgts[0];
    for (int j = 1; j < 16; ++j) m = fmaxf(m, lgts[j]);
    float ex[16], sum = 0.f;
    for (int j = 0; j < 16; ++j) { ex[j] = expf(lgts[j] - m); sum += ex[j]; }
    for (int j = 0; j < 16; ++j) out[b * 16 + j] = ex[j] / sum;
  }
}

extern "C" void kernel_launch(void* const* d_in, const int* in_sizes, int n_in,
                              void* d_out, int out_size, void* d_ws, size_t ws_size,
                              hipStream_t stream) {
  (void)in_sizes; (void)n_in; (void)out_size; (void)ws_size;
  const float* x  = (const float*)d_in[0];      // [NMAX, 32] f32
  const float* ea = (const float*)d_in[1];      // [E, 8]     f32
  const int*   ei = (const int*)d_in[2];        // [2, E]

  const float *gWl[3], *gbl[3], *gWr[3], *gbr[3], *gWe[3], *gatt[3], *gb[3], *pw[3];
  for (int l = 0; l < 3; ++l) {
    int p0 = 4 + 7 * l;
    gWl[l]  = (const float*)d_in[p0 + 0];
    gbl[l]  = (const float*)d_in[p0 + 1];
    gWr[l]  = (const float*)d_in[p0 + 2];
    gbr[l]  = (const float*)d_in[p0 + 3];
    gWe[l]  = (const float*)d_in[p0 + 4];
    gatt[l] = (const float*)d_in[p0 + 5];
    gb[l]   = (const float*)d_in[p0 + 6];
    pw[l]   = (const float*)d_in[25 + l];
  }
  const float* fc1W = (const float*)d_in[28];
  const float* fc1b = (const float*)d_in[29];
  const float* fc2W = (const float*)d_in[30];
  const float* fc2b = (const float*)d_in[31];
  const float* fc3W = (const float*)d_in[32];
  const float* fc3b = (const float*)d_in[33];

  // ---- workspace carve. cnt|rblk|csr CONTIGUOUS (all sizes %256==0): ONE memset ----
  char* w = (char*)d_ws;
  size_t off = 0;
  auto alloc = [&](size_t bytes) -> void* {
    void* p = w + off;
    off += (bytes + 255) & ~(size_t)255;
    return p;
  };
  float* hbuf = (float*)alloc((size_t)B_ * 1268 * 64 * 4); // pooled features (max K1)
  float* xl   = (float*)alloc((size_t)NMAX * 256 * 4);     // source transform [N,256]
  float* xr   = (float*)alloc((size_t)NMAX * 256 * 4);     // target transform [N,256]
  float* nacc = (float*)alloc((size_t)NMAX * 64 * 4);      // fused GAT output (pre-pool)
  int*   cnt  = (int*)alloc((size_t)NMAX * 4);             // CSR degree counters
  char*  rblk = (char*)alloc(3 * 32 * 128 * 4);            // per-layer [rsum][rmaxI] x3
  int*   csr  = (int*)alloc((size_t)NMAX * MAXDEG * 4);
  float* sbuf = (float*)alloc((size_t)NMAX * 4);
  int* src    = (int*)alloc((size_t)E_TOT * 4);
  int* dst    = (int*)alloc((size_t)E_TOT * 4);
  int* em     = (int*)alloc((size_t)E_TOT * 4);
  int* new_id = (int*)alloc((size_t)NMAX * 4);
  int* perm   = (int*)alloc((size_t)32 * 1268 * 4);

  // one-time zero of cnt + rblk + csr (csr zero => every slot is an in-bounds edge id
  // forever, enabling k_gat_fused's unconditional csr/srcv prefetch)
  size_t zbytes = (size_t)NMAX * 4 + 3 * 32 * 128 * 4 + (size_t)NMAX * MAXDEG * 4;
  hipMemsetAsync(cnt, 0, zbytes, stream);

  const int Ns[3]    = {50688, 40576, 32480};   // B*N0, B*K1, B*K2 (all %16==0)
  const int npers[3] = {1584, 1268, 1015};
  const int ks[3]    = {1268, 1015, 812};
  const int GAT_BLOCKS = 2048;                  // 8 XCD x 4 graphs x 64 blocks

  for (int l = 0; l < 3; ++l) {
    int N = Ns[l];
    const float* hin = (l == 0) ? x : hbuf;
    float* rsum = (float*)(rblk + l * 32 * 128 * 4);
    u32* rmaxI  = (u32*)(rblk + l * 32 * 128 * 4 + 32 * 64 * 4);
    if (l == 0)
      k_tre<<<TRE_TBLK + TRE_EBLK, 256, 0, stream>>>(hin, gWl[l], gbl[l], gWr[l], gbr[l],
                                                     xl, xr, ei, src, dst, em, cnt, csr);
    else
      k_transform_t<64><<<N / 16, 256, 0, stream>>>(hin, gWl[l], gbl[l], gWr[l], gbr[l], xl, xr);
    k_gat_fused<<<GAT_BLOCKS, 256, 0, stream>>>(src, cnt, csr, ea, gWe[l], gatt[l],
                                                xl, xr, gb[l], pw[l], nacc, sbuf, npers[l]);
    k_topk<<<32, 1024, 0, stream>>>(sbuf, npers[l], ks[l], perm, new_id, cnt);
    int grows = CDIV(ks[l], 4);
    dim3 pgrid(32, grows + (l < 2 ? REMAP_Y : 0));
    k_post<<<pgrid, 256, 0, stream>>>(nacc, sbuf, perm, hbuf, ks[l], grows, rsum, rmaxI,
                                      src, dst, em, new_id, cnt, csr, (l < 2) ? 1 : 0);
  }
  k_mlp<<<32, 64, 0, stream>>>(rblk, fc1W, fc1b, fc2W, fc2b, fc3W, fc3b, (float*)d_out);
}